// Round 4
// baseline (105.770 us; speedup 1.0000x reference)
//
#include <hip/hip_runtime.h>
#include <math.h>

// Shapes from reference: B=4, N=256, D=128, M=128, C=128
#define BB 4
#define NN 256
#define DD 128
#define MM 128
#define CC 128
#define ROWS (BB * NN)   // 1024

static __device__ __forceinline__ float fast_exp2(float x) {
#if __has_builtin(__builtin_amdgcn_exp2f)
    return __builtin_amdgcn_exp2f(x);
#else
    return __exp2f(x);
#endif
}

static __device__ __forceinline__ float fast_rcp(float x) {
#if __has_builtin(__builtin_amdgcn_rcpf)
    return __builtin_amdgcn_rcpf(x);
#else
    return 1.0f / x;
#endif
}

// silu(x) = x / (1 + exp(-x)); exp(-x) = 2^(-x*log2(e))
static __device__ __forceinline__ float silu_f(float x) {
    float e = fast_exp2(-1.44269504088896340736f * x);
    return x * fast_rcp(1.0f + e);
}

// ---------------------------------------------------------------------------
// Kernel 1: pibias = h@W1a + b1 ; pj = h@W1b
// 256 blocks (R=4 rows), 256 threads: k = t&127 (col m), rh = t>>7 (row pair).
// Weights burst-staged into LDS in 4 chunks of 32 KB (16 KB per matrix):
// 8 independent dwordx4 loads per thread per chunk -> one latency, not 32.
// ---------------------------------------------------------------------------
template <int R>
__global__ __launch_bounds__(256) void k_proj(const float* __restrict__ h,
                                              const float* __restrict__ W1a,
                                              const float* __restrict__ W1b,
                                              const float* __restrict__ b1,
                                              float* __restrict__ pibias,
                                              float* __restrict__ pj) {
    __shared__ float sWa[32 * MM];   // 16 KB: W1a[d0:d0+32, :]
    __shared__ float sWb[32 * MM];   // 16 KB
    __shared__ float sH[R * DD];     // 2 KB

    const int t = threadIdx.x;
    const int m = t & 127;
    const int rh = t >> 7;               // handles rows rh*2, rh*2+1
    const int row0 = blockIdx.x * R;

    const float bias = b1[m];            // hoisted: issue load early

    // Stage h rows (512 floats, coalesced).
    const float* hbase = h + (size_t)row0 * DD;
    sH[t] = hbase[t];
    sH[t + 256] = hbase[t + 256];

    float accA[2] = {0.0f, 0.0f};
    float accB[2] = {0.0f, 0.0f};

    for (int c = 0; c < 4; ++c) {
        __syncthreads();                 // protect previous chunk readers (and sH on c=0)
        // Burst-stage 32 d-rows of each weight matrix.
        const float4* ga = (const float4*)(W1a + (size_t)c * 32 * MM);
        const float4* gb = (const float4*)(W1b + (size_t)c * 32 * MM);
        float4* la = (float4*)sWa;
        float4* lb = (float4*)sWb;
        #pragma unroll
        for (int i = 0; i < 4; ++i) {
            la[t + 256 * i] = ga[t + 256 * i];
            lb[t + 256 * i] = gb[t + 256 * i];
        }
        __syncthreads();

        #pragma unroll 8
        for (int dd = 0; dd < 32; ++dd) {
            const int d = c * 32 + dd;
            const float wa = sWa[dd * MM + m];
            const float wb = sWb[dd * MM + m];
            #pragma unroll
            for (int r = 0; r < 2; ++r) {
                const float hv = sH[(rh * 2 + r) * DD + d];  // wave-uniform broadcast
                accA[r] = fmaf(hv, wa, accA[r]);
                accB[r] = fmaf(hv, wb, accB[r]);
            }
        }
    }

    #pragma unroll
    for (int r = 0; r < 2; ++r) {
        const int row = row0 + rh * 2 + r;
        pibias[(size_t)row * MM + m] = accA[r] + bias;
        pj[(size_t)row * MM + m]     = accB[r];
    }
}

// ---------------------------------------------------------------------------
// Kernel 2: 2 rows (same batch) per block, 512 blocks, 256 threads.
//   S[row][m] = inv * sum_{j != i} adj[row][j] * silu(pibias[row][m] + pj[b,j][m])
//   beta[row] = inv * sum_{j != i} adj[row][j]
// pj batch slice burst-staged in 4 chunks of 32 KB (64 j-rows each).
// ---------------------------------------------------------------------------
__global__ __launch_bounds__(256) void k_msg(const float* __restrict__ adj,
                                             const float* __restrict__ pibias,
                                             const float* __restrict__ pj,
                                             float* __restrict__ S,
                                             float* __restrict__ beta) {
    __shared__ float sPJ[64 * MM];    // 32 KB: pj[j0:j0+64, :]
    __shared__ float sAdj[2][NN];     // 2 KB
    __shared__ float sRed[2][256];    // 2 KB
    __shared__ float sWred[2][4];

    const int t = threadIdx.x;
    const int pairIdx = blockIdx.x;       // 512 blocks
    const int b = pairIdx >> 7;
    const int i0 = (pairIdx & 127) * 2;
    const int row0 = b * NN + i0;

    const int m = t & 127;
    const int jh = t >> 7;

    // Early loads (independent): adj rows, pibias rows.
    const float* arow = adj + (size_t)row0 * NN;
    const float a0v = arow[t];
    const float a1v = arow[t + 256];
    const float pim0 = pibias[(size_t)row0 * MM + m];
    const float pim1 = pibias[(size_t)(row0 + 1) * MM + m];

    sAdj[0][t] = a0v;
    sAdj[1][t] = a1v;
    __syncthreads();

    // Row sums via wave shuffle + tiny LDS combine.
    float v0 = a0v, v1 = a1v;
    #pragma unroll
    for (int off = 32; off > 0; off >>= 1) {
        v0 += __shfl_xor(v0, off, 64);
        v1 += __shfl_xor(v1, off, 64);
    }
    if ((t & 63) == 0) { sWred[0][t >> 6] = v0; sWred[1][t >> 6] = v1; }
    __syncthreads();
    const float A0 = sWred[0][0] + sWred[0][1] + sWred[0][2] + sWred[0][3];
    const float A1 = sWred[1][0] + sWred[1][1] + sWred[1][2] + sWred[1][3];
    const float aii0 = sAdj[0][i0];
    const float aii1 = sAdj[1][i0 + 1];
    __syncthreads();                      // all reads done before zeroing
    if (t == 0) { sAdj[0][i0] = 0.0f; sAdj[1][i0 + 1] = 0.0f; }
    // (next __syncthreads happens at top of chunk loop)

    const float inv0 = 1.0f / fmaxf(A0, 1.0f);
    const float inv1 = 1.0f / fmaxf(A1, 1.0f);

    const float* __restrict__ pjB = pj + (size_t)b * NN * MM;

    float acc0 = 0.0f, acc1 = 0.0f;
    for (int c = 0; c < 4; ++c) {
        __syncthreads();
        const float4* g = (const float4*)(pjB + (size_t)c * 64 * MM);
        float4* l = (float4*)sPJ;
        #pragma unroll
        for (int i = 0; i < 8; ++i) l[t + 256 * i] = g[t + 256 * i];
        __syncthreads();

        #pragma unroll 8
        for (int jj = jh; jj < 64; jj += 2) {
            const int j = c * 64 + jj;
            const float pjv = sPJ[jj * MM + m];   // stride-1: conflict-free
            const float w0 = sAdj[0][j];          // wave-uniform broadcast
            const float w1 = sAdj[1][j];
            acc0 = fmaf(w0, silu_f(pim0 + pjv), acc0);
            acc1 = fmaf(w1, silu_f(pim1 + pjv), acc1);
        }
    }

    sRed[0][t] = acc0;
    sRed[1][t] = acc1;
    __syncthreads();
    if (t < 128) {
        S[(size_t)row0 * MM + t] = (sRed[0][t] + sRed[0][t + 128]) * inv0;
    } else {
        const int k = t - 128;
        S[(size_t)(row0 + 1) * MM + k] = (sRed[1][k] + sRed[1][k + 128]) * inv1;
    }
    if (t == 0) {
        beta[row0]     = (A0 - aii0) * inv0;
        beta[row0 + 1] = (A1 - aii1) * inv1;
    }
}

// ---------------------------------------------------------------------------
// Kernel 3: fused head. magg = S@W2 + beta*b2 ; t1 = silu(magg@Wc1+bc1) ;
// out = t1@Wc2 + bc2. 256 blocks (R=4), 256 threads: k = t&127, rh = t>>7.
// Each weight matrix burst-staged in 2 chunks of 32 KB.
// ---------------------------------------------------------------------------
__device__ __forceinline__ void matvec_staged(const float* __restrict__ W,
                                              const float* __restrict__ src,  // [4][MM] flat
                                              float* __restrict__ sW,
                                              float acc[2], int t, int k, int rh) {
    for (int c = 0; c < 2; ++c) {
        __syncthreads();   // protects sW readers of prev chunk AND src writers
        const float4* g = (const float4*)(W + (size_t)c * 64 * MM);
        float4* l = (float4*)sW;
        #pragma unroll
        for (int i = 0; i < 8; ++i) l[t + 256 * i] = g[t + 256 * i];
        __syncthreads();

        #pragma unroll 8
        for (int dd = 0; dd < 64; ++dd) {
            const int d = c * 64 + dd;
            const float wv = sW[dd * MM + k];     // stride-1: conflict-free
            acc[0] = fmaf(src[(rh * 2 + 0) * MM + d], wv, acc[0]);  // uniform
            acc[1] = fmaf(src[(rh * 2 + 1) * MM + d], wv, acc[1]);
        }
    }
}

template <int R>
__global__ __launch_bounds__(256) void k_out(const float* __restrict__ S,
                                             const float* __restrict__ beta,
                                             const float* __restrict__ W2,
                                             const float* __restrict__ b2,
                                             const float* __restrict__ Wc1,
                                             const float* __restrict__ bc1,
                                             const float* __restrict__ Wc2,
                                             const float* __restrict__ bc2,
                                             float* __restrict__ out) {
    __shared__ float sW[64 * MM];     // 32 KB weight chunk
    __shared__ float sA[R * MM];      // 2 KB activations (ping)
    __shared__ float sB[R * MM];      // 2 KB activations (pong)

    const int t = threadIdx.x;
    const int k = t & 127;
    const int rh = t >> 7;
    const int row0 = blockIdx.x * R;

    // Early independent loads.
    const float bet0 = beta[row0 + rh * 2];
    const float bet1 = beta[row0 + rh * 2 + 1];
    const float b2k  = b2[k];
    const float bc1k = bc1[k];
    const float bc2k = bc2[k];

    const float* sbase = S + (size_t)row0 * MM;
    sA[t] = sbase[t];
    sA[t + 256] = sbase[t + 256];
    // (sync handled inside matvec_staged before sW staging)

    float acc[2];

    // ---- Stage 1: magg = S@W2 + beta*b2  (sA -> sB)
    acc[0] = bet0 * b2k;
    acc[1] = bet1 * b2k;
    matvec_staged(W2, sA, sW, acc, t, k, rh);
    sB[(rh * 2 + 0) * MM + k] = acc[0];
    sB[(rh * 2 + 1) * MM + k] = acc[1];

    // ---- Stage 2: t1 = silu(magg@Wc1 + bc1)  (sB -> sA)
    acc[0] = bc1k;
    acc[1] = bc1k;
    matvec_staged(Wc1, sB, sW, acc, t, k, rh);   // first sync inside covers sB writes
    sA[(rh * 2 + 0) * MM + k] = silu_f(acc[0]);
    sA[(rh * 2 + 1) * MM + k] = silu_f(acc[1]);

    // ---- Stage 3: out = t1@Wc2 + bc2  (sA -> global)
    acc[0] = bc2k;
    acc[1] = bc2k;
    matvec_staged(Wc2, sA, sW, acc, t, k, rh);
    out[(size_t)(row0 + rh * 2 + 0) * CC + k] = acc[0];
    out[(size_t)(row0 + rh * 2 + 1) * CC + k] = acc[1];
}

extern "C" void kernel_launch(void* const* d_in, const int* in_sizes, int n_in,
                              void* d_out, int out_size, void* d_ws, size_t ws_size,
                              hipStream_t stream) {
    const float* h   = (const float*)d_in[0];
    const float* adj = (const float*)d_in[1];
    const float* W1a = (const float*)d_in[2];
    const float* W1b = (const float*)d_in[3];
    const float* b1  = (const float*)d_in[4];
    const float* W2  = (const float*)d_in[5];
    const float* b2  = (const float*)d_in[6];
    const float* Wc1 = (const float*)d_in[7];
    const float* bc1 = (const float*)d_in[8];
    const float* Wc2 = (const float*)d_in[9];
    const float* bc2 = (const float*)d_in[10];
    float* out = (float*)d_out;

    // Workspace (floats): pibias[1024*128] | pj[1024*128] | S[1024*128] | beta[1024]
    float* ws = (float*)d_ws;
    float* pibias = ws;
    float* pj     = ws + (size_t)ROWS * MM;
    float* S      = ws + (size_t)2 * ROWS * MM;
    float* beta   = ws + (size_t)3 * ROWS * MM;

    k_proj<4><<<ROWS / 4, 256, 0, stream>>>(h, W1a, W1b, b1, pibias, pj);
    k_msg<<<ROWS / 2, 256, 0, stream>>>(adj, pibias, pj, S, beta);
    k_out<4><<<ROWS / 4, 256, 0, stream>>>(S, beta, W2, b2, Wc1, bc1, Wc2, bc2, out);
}